// Round 15
// baseline (3831.253 us; speedup 1.0000x reference)
//
#include <hip/hip_runtime.h>
#include <cstdint>
#include <cstddef>

constexpr int CC = 320;     // channels
constexpr int NN = 3136;    // tokens (56*56)
constexpr int BB = 2;       // batch
constexpr int RR = BB * NN; // 6272 rows
constexpr float BN_INV_F = 0.9999950000374997f; // 1/sqrt(1+1e-5)
constexpr int MB = 98;      // m-blocks (64-row tiles) for gemm_t
constexpr int SWZ = ((MB + 7) / 8) * 8 * 5; // 520 swizzled blocks

// ---------------- weight transposes: (l, co, ci) -> (l, ci, co) ----------------
__global__ __launch_bounds__(256) void transpose6(
    const float* __restrict__ w0, const float* __restrict__ w1,
    const float* __restrict__ w2, const float* __restrict__ w3,
    const float* __restrict__ w4, const float* __restrict__ w5,
    float* __restrict__ out) {
  size_t e = (size_t)blockIdx.x * 256 + threadIdx.x;
  const size_t per = (size_t)6 * CC * CC;
  if (e >= 6 * per) return;
  int m = (int)(e / per);
  size_t r = e % per;
  int l = (int)(r / (CC * CC));
  int q = (int)(r % (CC * CC));
  int ci = q / CC, co = q % CC;
  const float* src = (m == 0) ? w0 : (m == 1) ? w1 : (m == 2) ? w2
                   : (m == 3) ? w3 : (m == 4) ? w4 : w5;
  out[e] = src[(size_t)l * CC * CC + (size_t)co * CC + ci];
}

__global__ __launch_bounds__(256) void transpose_gc(const float* __restrict__ w,
                                                    float* __restrict__ out) {
  size_t e = (size_t)blockIdx.x * 256 + threadIdx.x;
  const size_t tot = (size_t)6 * 2 * CC * CC;
  if (e >= tot) return;
  int l = (int)(e / (2 * CC * CC));
  int q = (int)(e % (2 * CC * CC));
  int ci = q / CC, co = q % CC; // ci in [0,640)
  out[e] = w[(size_t)l * CC * 2 * CC + (size_t)co * 2 * CC + ci];
}

// w1 (160,3,3,3) OIHW -> (27,160)
__global__ __launch_bounds__(256) void transpose_w1(const float* __restrict__ w,
                                                    float* __restrict__ out) {
  int e = blockIdx.x * 256 + threadIdx.x;
  if (e >= 160 * 27) return;
  int oc = e / 27, k = e % 27;
  out[k * 160 + oc] = w[e];
}

// conv weight (320, K) -> (K, 320); k = ic*9+khw is the NATIVE inner order of OIHW
template <int K>
__global__ __launch_bounds__(256) void transpose_conv(const float* __restrict__ w,
                                                      float* __restrict__ out) {
  int e = blockIdx.x * 256 + threadIdx.x;
  if (e >= K * 320) return;
  int k = e / 320, co = e % 320;
  out[e] = w[(size_t)co * K + k];
}

// ---------------- conv1 direct: NCHW input -> NHWC output, bias+BN+relu ----------------
__global__ __launch_bounds__(160) void conv1_kernel(const float* __restrict__ x,
                                                    const float* __restrict__ w1t,
                                                    const float* __restrict__ cb,
                                                    const float* __restrict__ g,
                                                    const float* __restrict__ bt,
                                                    float* __restrict__ C1) {
  int pix = blockIdx.x;
  int oc = threadIdx.x;
  int b = pix / 12544;
  int r = pix % 12544;
  int oh = r / 112, ow = r % 112;
  int ih0 = 2 * oh - 1, iw0 = 2 * ow - 1;
  float acc = 0.f;
#pragma unroll
  for (int ic = 0; ic < 3; ic++) {
    const float* xc = x + ((size_t)(b * 3 + ic)) * 224 * 224;
#pragma unroll
    for (int kh = 0; kh < 3; kh++) {
      int ih = ih0 + kh;
      if (ih < 0 || ih >= 224) continue;
#pragma unroll
      for (int kw = 0; kw < 3; kw++) {
        int iw = iw0 + kw;
        if (iw < 0 || iw >= 224) continue;
        acc = fmaf(xc[(size_t)ih * 224 + iw], w1t[(ic * 9 + kh * 3 + kw) * 160 + oc], acc);
      }
    }
  }
  float y = (acc + cb[oc]) * (BN_INV_F * g[oc]) + bt[oc];
  C1[(size_t)pix * 160 + oc] = fmaxf(y, 0.f);
}

// ---------------- im2col with k = ic*9 + khw (zero-padded OOB; bit-exact via fmaf(0,w,a)=a) ----
template <int CIN, int IH, int IW, int S>
__global__ __launch_bounds__(256) void im2col_k(const float* __restrict__ src,
                                                float* __restrict__ COL) {
  constexpr int K = CIN * 9;
  int row = blockIdx.x;
  int b = row / 3136, pix = row % 3136;
  int oh = pix / 56, ow = pix % 56;
  int ih0 = S * oh - 1, iw0 = S * ow - 1;
  float* dst = COL + (size_t)row * K;
  for (int k = threadIdx.x; k < K; k += 256) {
    int ic = k / 9;
    int khw = k - ic * 9;
    int kh = khw / 3, kw = khw - kh * 3;
    int ih = ih0 + kh, iw = iw0 + kw;
    float v = 0.f;
    if (ih >= 0 && ih < IH && iw >= 0 && iw < IW)
      v = src[(((size_t)(b * IH + ih)) * IW + iw) * CIN + ic];
    dst[k] = v;
  }
}

// ---------------- expmap0 over channels (token-major NHWC input) + pos embed ----------------
__global__ __launch_bounds__(CC) void expmap_tok_kernel(const float* __restrict__ h,
                                                        const float* __restrict__ pos,
                                                        float* __restrict__ X) {
  int bn = blockIdx.x;
  int n = bn % NN;
  int c = threadIdx.x;
  float u = h[(size_t)bn * CC + c] + pos[(size_t)c * NN + n];
  float v = (c == 0) ? 0.f : u * u;
#pragma unroll
  for (int o = 32; o > 0; o >>= 1) v += __shfl_down(v, o, 64);
  __shared__ float red[5];
  __shared__ float fac[2];
  if ((c & 63) == 0) red[c >> 6] = v;
  __syncthreads();
  if (c == 0) {
    float s = red[0] + red[1] + red[2] + red[3] + red[4];
    float nrm = sqrtf(fmaxf(s, 1e-8f));
    fac[0] = coshf(nrm);
    fac[1] = sinhf(nrm) / nrm;
  }
  __syncthreads();
  X[(size_t)bn * CC + c] = (c == 0) ? fac[0] : fac[1] * u;
}

// ---------------- P permutation: V[n*C+c] = U[c*N+n]  (+ optional add[n*C+c]) ----------------
__global__ __launch_bounds__(256) void pperm_kernel(const float* __restrict__ U,
                                                    const float* __restrict__ add,
                                                    float* __restrict__ V) {
  __shared__ float t[64][65];
  int b = blockIdx.z;
  int n0 = blockIdx.x * 64;
  int c0 = blockIdx.y * 64;
  const float* Ub = U + (size_t)b * NN * CC;
  float* Vb = V + (size_t)b * NN * CC;
  const float* Ab = add ? add + (size_t)b * NN * CC : nullptr;
  int tx = threadIdx.x & 63;
  int ty = threadIdx.x >> 6; // 0..3
#pragma unroll
  for (int i = 0; i < 16; i++) {
    int c = ty * 16 + i;
    t[c][tx] = Ub[(size_t)(c0 + c) * NN + n0 + tx];
  }
  __syncthreads();
#pragma unroll
  for (int i = 0; i < 16; i++) {
    int n = ty * 16 + i;
    float v = t[tx][n];
    size_t o = (size_t)(n0 + n) * CC + c0 + tx;
    if (Ab) v += Ab[o];
    Vb[o] = v;
  }
}

// ---------------- GEMM: C[M,320] = op(A[M,K]) @ WT[K,320] + epilogue ----------------
// 64x64 tile, 128 threads, 8x4 microtile, BK=32, software-pipelined staging,
// XCD-aware swizzled 1D grid (SWZ blocks): the 5 n-blocks of one m-tile share
// id%8 => same XCD => A-tile L2 reuse. Per-output k ascends with one accumulator
// => bit-identical.
// AMODE: 0 = raw A; 1 = relu(A); 2 = relu(LorentzNorm via per-row (tmv,rf) in NS)
// EPI: 0 = +bias; 1 = (acc+bias)*(BN_INV*g)+bt; 2 = EPI1 + relu
template <int AMODE, int EPI>
__global__ __launch_bounds__(128) void gemm_t(const float* __restrict__ A,
                                              const float* __restrict__ BW,
                                              const float* __restrict__ bias,
                                              const float* __restrict__ bng,
                                              const float* __restrict__ bnb,
                                              const float2* __restrict__ NS,
                                              float* __restrict__ C, int K) {
  __shared__ float As[32][68];
  __shared__ float Bs[32][68];
  int g = blockIdx.x;
  int mlocal = g & 7;
  int rest = g >> 3;
  int nb = rest % 5;
  int mg = rest / 5;
  int m = mg * 8 + mlocal;
  if (m >= MB) return;
  int n0 = nb * 64;
  int m0 = m * 64;
  int tid = threadIdx.x;
  int lm = tid >> 1;           // 0..63
  int lk8 = (tid & 1) * 8;     // 0 or 8
  int bk = tid >> 4;           // 0..7
  int bn = (tid & 15) << 2;    // 0..60
  int tm = (tid >> 4) << 3;    // 0..56 step 8
  int tn = (tid & 15) << 2;    // 0..60
  float acc[8][4] = {};
  float4 ra[4], rb[4];
  const float* aprow = A + (size_t)(m0 + lm) * K + lk8;
  float ns_t = 0.f, ns_r = 0.f;
  if (AMODE == 2) {
    float2 nv = NS[m0 + lm];
    ns_t = nv.x;
    ns_r = nv.y;
  }

  auto load_tile = [&](int k0) {
    const float* ap = aprow + k0;
    ra[0] = *(const float4*)ap;
    ra[1] = *(const float4*)(ap + 4);
    ra[2] = *(const float4*)(ap + 16);
    ra[3] = *(const float4*)(ap + 20);
#pragma unroll
    for (int h = 0; h < 4; h++)
      rb[h] = *(const float4*)(BW + (size_t)(k0 + bk + h * 8) * CC + n0 + bn);
  };
  auto store_tile = [&](int k0) {
#pragma unroll
    for (int h = 0; h < 2; h++) {
      float4 a0 = ra[h * 2], a1 = ra[h * 2 + 1];
      if (AMODE == 2) {
        int kbg = k0 + lk8 + h * 16;
        a0.x = (kbg == 0) ? ns_t : a0.x * ns_r;
        a0.y *= ns_r; a0.z *= ns_r; a0.w *= ns_r;
        a1.x *= ns_r; a1.y *= ns_r; a1.z *= ns_r; a1.w *= ns_r;
      }
      if (AMODE >= 1) {
        a0.x = fmaxf(a0.x, 0.f); a0.y = fmaxf(a0.y, 0.f);
        a0.z = fmaxf(a0.z, 0.f); a0.w = fmaxf(a0.w, 0.f);
        a1.x = fmaxf(a1.x, 0.f); a1.y = fmaxf(a1.y, 0.f);
        a1.z = fmaxf(a1.z, 0.f); a1.w = fmaxf(a1.w, 0.f);
      }
      int kb = lk8 + h * 16;
      As[kb + 0][lm] = a0.x; As[kb + 1][lm] = a0.y;
      As[kb + 2][lm] = a0.z; As[kb + 3][lm] = a0.w;
      As[kb + 4][lm] = a1.x; As[kb + 5][lm] = a1.y;
      As[kb + 6][lm] = a1.z; As[kb + 7][lm] = a1.w;
    }
#pragma unroll
    for (int h = 0; h < 4; h++)
      *(float4*)&Bs[bk + h * 8][bn] = rb[h];
  };
  auto compute = [&]() {
#pragma unroll
    for (int k = 0; k < 32; k++) {
      float4 av0 = *(const float4*)&As[k][tm];
      float4 av1 = *(const float4*)&As[k][tm + 4];
      float4 bv = *(const float4*)&Bs[k][tn];
      float aa[8] = {av0.x, av0.y, av0.z, av0.w, av1.x, av1.y, av1.z, av1.w};
      float bb[4] = {bv.x, bv.y, bv.z, bv.w};
#pragma unroll
      for (int i = 0; i < 8; i++)
#pragma unroll
        for (int j = 0; j < 4; j++) acc[i][j] = fmaf(aa[i], bb[j], acc[i][j]);
    }
  };

  load_tile(0);
  store_tile(0);
  __syncthreads();
  for (int k0 = 32; k0 < K; k0 += 32) {
    load_tile(k0);   // in flight during compute
    compute();
    __syncthreads();
    store_tile(k0);
    __syncthreads();
  }
  compute();

  float4 bv = *(const float4*)(bias + n0 + tn);
  float bb[4] = {bv.x, bv.y, bv.z, bv.w};
  float gg[4], tt[4];
  if (EPI >= 1) {
    float4 gv = *(const float4*)(bng + n0 + tn);
    float4 tv = *(const float4*)(bnb + n0 + tn);
    gg[0] = gv.x; gg[1] = gv.y; gg[2] = gv.z; gg[3] = gv.w;
    tt[0] = tv.x; tt[1] = tv.y; tt[2] = tv.z; tt[3] = tv.w;
  }
#pragma unroll
  for (int i = 0; i < 8; i++) {
    float o[4];
#pragma unroll
    for (int j = 0; j < 4; j++) {
      float y = acc[i][j] + bb[j];
      if (EPI >= 1) y = y * (BN_INV_F * gg[j]) + tt[j];
      if (EPI == 2) y = fmaxf(y, 0.f);
      o[j] = y;
    }
    float4 ov = {o[0], o[1], o[2], o[3]};
    *(float4*)(C + (size_t)(m0 + tm + i) * CC + n0 + tn) = ov;
  }
}

// ---------------- Lorentz row normalization (+ optional residual) ----------------
__global__ __launch_bounds__(256) void lorentz_norm(const float* __restrict__ Y,
                                                    const float* __restrict__ logs, int l,
                                                    const float* __restrict__ res1,
                                                    float* __restrict__ out) {
  int lane = threadIdx.x & 63;
  size_t row = (size_t)blockIdx.x * 4 + (threadIdx.x >> 6);
  const float* y = Y + row * CC;
  float v[5];
  float ss = 0.f;
#pragma unroll
  for (int q = 0; q < 5; q++) {
    v[q] = y[q * 64 + lane];
    float z = v[q] * v[q];
    if (q == 0 && lane == 0) z = 0.f;
    ss += z;
  }
#pragma unroll
  for (int o = 32; o > 0; o >>= 1) ss += __shfl_down(ss, o, 64);
  ss = __shfl(ss, 0, 64);
  float y0 = __shfl(v[0], 0, 64);
  float scale = expf(logs[l]);
  float tmv = scale / (1.f + expf(-y0)) + 1.1f;
  float rf = sqrtf((tmv * tmv - 1.f) / fmaxf(ss, 1e-8f));
#pragma unroll
  for (int q = 0; q < 5; q++) {
    int c = q * 64 + lane;
    float o = (c == 0) ? tmv : v[q] * rf;
    if (res1) o += res1[row * CC + c];
    out[row * CC + c] = o;
  }
}

// ---------------- norm scalars only: NS[row] = (tmv, rf)  (exact lorentz_norm scalar path) ----
__global__ __launch_bounds__(256) void norm_scal(const float* __restrict__ Y,
                                                 const float* __restrict__ logs, int l,
                                                 float2* __restrict__ NS) {
  int lane = threadIdx.x & 63;
  size_t row = (size_t)blockIdx.x * 4 + (threadIdx.x >> 6);
  const float* y = Y + row * CC;
  float v[5];
  float ss = 0.f;
#pragma unroll
  for (int q = 0; q < 5; q++) {
    v[q] = y[q * 64 + lane];
    float z = v[q] * v[q];
    if (q == 0 && lane == 0) z = 0.f;
    ss += z;
  }
#pragma unroll
  for (int o = 32; o > 0; o >>= 1) ss += __shfl_down(ss, o, 64);
  ss = __shfl(ss, 0, 64);
  float y0 = __shfl(v[0], 0, 64);
  float scale = expf(logs[l]);
  float tmv = scale / (1.f + expf(-y0)) + 1.1f;
  float rf = sqrtf((tmv * tmv - 1.f) / fmaxf(ss, 1e-8f));
  if (lane == 0) NS[row] = make_float2(tmv, rf);
}

// ---------------- per-row squared norms ----------------
__global__ __launch_bounds__(256) void sq_kernel(const float* __restrict__ Y,
                                                 float* __restrict__ sq) {
  int lane = threadIdx.x & 63;
  size_t row = (size_t)blockIdx.x * 4 + (threadIdx.x >> 6);
  const float* y = Y + row * CC;
  float ss = 0.f;
#pragma unroll
  for (int q = 0; q < 5; q++) {
    float v = y[q * 64 + lane];
    ss += v * v;
  }
#pragma unroll
  for (int o = 32; o > 0; o >>= 1) ss += __shfl_down(ss, o, 64);
  if (lane == 0) sq[row] = ss;
}

// ---------------- symmetric distance, batched over B: upper-triangle tiles ----------------
__global__ __launch_bounds__(128) void dist_gemm_sym(const float* __restrict__ Yall,
                                                     const float* __restrict__ sqall,
                                                     float* __restrict__ Dall) {
  __shared__ float S[2][32][68];
  auto As = S[0];
  auto Bs = S[1];
  int tid = threadIdx.x;
  int batch = blockIdx.y;
  const float* Y = Yall + (size_t)batch * NN * CC;
  const float* sq = sqall + (size_t)batch * NN;
  float* D = Dall + (size_t)batch * NN * NN;
  int t = blockIdx.x;
  int bi = 0, rem = t;
  while (rem >= 49 - bi) { rem -= 49 - bi; bi++; }
  int bj = bi + rem;
  int i0 = bi * 64, j0 = bj * 64;
  int lm = tid >> 1;
  int lk8 = (tid & 1) * 8;
  int tm = (tid >> 4) << 3;
  int tn = (tid & 15) << 2;
  float acc[8][4] = {};
  float4 ra[4], rb[4];
  const float* aprow = Y + (size_t)(i0 + lm) * CC + lk8;
  const float* bprow = Y + (size_t)(j0 + lm) * CC + lk8;

  auto load_tile = [&](int k0) {
    const float* ap = aprow + k0;
    ra[0] = *(const float4*)ap;
    ra[1] = *(const float4*)(ap + 4);
    ra[2] = *(const float4*)(ap + 16);
    ra[3] = *(const float4*)(ap + 20);
    const float* bp = bprow + k0;
    rb[0] = *(const float4*)bp;
    rb[1] = *(const float4*)(bp + 4);
    rb[2] = *(const float4*)(bp + 16);
    rb[3] = *(const float4*)(bp + 20);
  };
  auto store_tile = [&]() {
#pragma unroll
    for (int h = 0; h < 2; h++) {
      int kb = lk8 + h * 16;
      float4 a0 = ra[h * 2], a1 = ra[h * 2 + 1];
      As[kb + 0][lm] = a0.x; As[kb + 1][lm] = a0.y;
      As[kb + 2][lm] = a0.z; As[kb + 3][lm] = a0.w;
      As[kb + 4][lm] = a1.x; As[kb + 5][lm] = a1.y;
      As[kb + 6][lm] = a1.z; As[kb + 7][lm] = a1.w;
      float4 b0 = rb[h * 2], b1 = rb[h * 2 + 1];
      Bs[kb + 0][lm] = b0.x; Bs[kb + 1][lm] = b0.y;
      Bs[kb + 2][lm] = b0.z; Bs[kb + 3][lm] = b0.w;
      Bs[kb + 4][lm] = b1.x; Bs[kb + 5][lm] = b1.y;
      Bs[kb + 6][lm] = b1.z; Bs[kb + 7][lm] = b1.w;
    }
  };
  auto compute = [&]() {
#pragma unroll
    for (int k = 0; k < 32; k++) {
      float4 av0 = *(const float4*)&As[k][tm];
      float4 av1 = *(const float4*)&As[k][tm + 4];
      float4 bv = *(const float4*)&Bs[k][tn];
      float aa[8] = {av0.x, av0.y, av0.z, av0.w, av1.x, av1.y, av1.z, av1.w};
      float bb[4] = {bv.x, bv.y, bv.z, bv.w};
#pragma unroll
      for (int i = 0; i < 8; i++)
#pragma unroll
        for (int j = 0; j < 4; j++) acc[i][j] = fmaf(aa[i], bb[j], acc[i][j]);
    }
  };

  load_tile(0);
  store_tile();
  __syncthreads();
  for (int k0 = 32; k0 < CC; k0 += 32) {
    load_tile(k0);
    compute();
    __syncthreads();
    store_tile();
    __syncthreads();
  }
  compute();

  float sqi[8], sqj[4];
#pragma unroll
  for (int i = 0; i < 8; i++) sqi[i] = sq[i0 + tm + i];
#pragma unroll
  for (int j = 0; j < 4; j++) sqj[j] = sq[j0 + tn + j];
  float o[8][4];
#pragma unroll
  for (int i = 0; i < 8; i++) {
#pragma unroll
    for (int j = 0; j < 4; j++)
      o[i][j] = sqi[i] + sqj[j] - 2.f * acc[i][j];
    float4 ov = {o[i][0], o[i][1], o[i][2], o[i][3]};
    *(float4*)(D + (size_t)(i0 + tm + i) * NN + j0 + tn) = ov;
  }
  if (bi != bj) {
    __syncthreads();
    float* flat = &S[0][0][0];
#pragma unroll
    for (int i = 0; i < 8; i++)
#pragma unroll
      for (int j = 0; j < 4; j++)
        flat[(tn + j) * 65 + tm + i] = o[i][j];
    __syncthreads();
#pragma unroll
    for (int r = 0; r < 4; r++) {
      int row = tn + r;
      float4 w0, w1;
      w0.x = flat[row * 65 + tm + 0]; w0.y = flat[row * 65 + tm + 1];
      w0.z = flat[row * 65 + tm + 2]; w0.w = flat[row * 65 + tm + 3];
      w1.x = flat[row * 65 + tm + 4]; w1.y = flat[row * 65 + tm + 5];
      w1.z = flat[row * 65 + tm + 6]; w1.w = flat[row * 65 + tm + 7];
      *(float4*)(D + (size_t)(j0 + row) * NN + i0 + tm) = w0;
      *(float4*)(D + (size_t)(j0 + row) * NN + i0 + tm + 4) = w1;
    }
  }
}

// ---------------- exact top-k, batched over B (jax tie-break), wave per row ----------------
template <int KT, int DIL>
__global__ __launch_bounds__(256) void topk_kernel(const float* __restrict__ Dall,
                                                   int* __restrict__ idxall) {
  int lane = threadIdx.x & 63;
  int batch = blockIdx.y;
  int row = blockIdx.x * 4 + (threadIdx.x >> 6); // row within one batch
  const float* d = Dall + (size_t)batch * NN * NN + (size_t)row * NN;
  int* idxout = idxall + (size_t)batch * NN * 9;
  float ld[KT];
  int li[KT];
#pragma unroll
  for (int q = 0; q < KT; q++) { ld[q] = 3.4e38f; li[q] = 0x7FFFFFFF; }
  for (int t = 0; t < NN / 64; t++) {
    int j = t * 64 + lane;
    float x = d[j];
    if (x < ld[KT - 1]) {
      ld[KT - 1] = x;
      li[KT - 1] = j;
#pragma unroll
      for (int p = KT - 1; p > 0; p--) {
        if (ld[p] < ld[p - 1]) {
          float tf = ld[p]; ld[p] = ld[p - 1]; ld[p - 1] = tf;
          int ti = li[p]; li[p] = li[p - 1]; li[p - 1] = ti;
        }
      }
    }
  }
#pragma unroll 1
  for (int q = 0; q < KT; q++) {
    float bd = ld[0];
    int bi = li[0];
#pragma unroll
    for (int s = 32; s > 0; s >>= 1) {
      float od = __shfl_xor(bd, s, 64);
      int oi = __shfl_xor(bi, s, 64);
      if (od < bd || (od == bd && oi < bi)) { bd = od; bi = oi; }
    }
    if (ld[0] == bd && li[0] == bi) {
#pragma unroll
      for (int p = 0; p < KT - 1; p++) { ld[p] = ld[p + 1]; li[p] = li[p + 1]; }
      ld[KT - 1] = 3.4e38f;
      li[KT - 1] = 0x7FFFFFFF;
    }
    if (lane == 0 && (q % DIL) == 0) idxout[(size_t)row * 9 + q / DIL] = bi;
  }
}

// ---------------- neighbor max + concat [f, max_j f_j - f_i] ----------------
__global__ __launch_bounds__(CC) void gather_max_cat(const float* __restrict__ Y,
                                                     const int* __restrict__ idx,
                                                     float* __restrict__ cat) {
  int bn = blockIdx.x;
  int c = threadIdx.x;
  int b = bn / NN;
  float yc = Y[(size_t)bn * CC + c];
  const int* ip = idx + (size_t)bn * 9;
  float mx = -3.4e38f;
#pragma unroll
  for (int q = 0; q < 9; q++) {
    int j = ip[q];
    mx = fmaxf(mx, Y[((size_t)b * NN + j) * CC + c]);
  }
  cat[(size_t)bn * 2 * CC + c] = yc;
  cat[(size_t)bn * 2 * CC + CC + c] = mx - yc;
}

// ---------------- pooling + head ----------------
__global__ __launch_bounds__(CC) void pool_kernel(const float* __restrict__ X,
                                                  float* __restrict__ pooled) {
  int b = blockIdx.y;
  int chunk = blockIdx.x;
  int c = threadIdx.x;
  const float* p = X + ((size_t)b * NN + (size_t)chunk * 64) * CC + c;
  float s = 0.f;
#pragma unroll
  for (int q = 0; q < 64; q++) s += p[(size_t)q * CC];
  atomicAdd(&pooled[b * CC + c], s);
}

__global__ __launch_bounds__(256) void head_kernel(const float* __restrict__ pooled,
                                                   const float* __restrict__ clsw,
                                                   const float* __restrict__ hb,
                                                   float* __restrict__ out) {
  int t = blockIdx.x * 256 + threadIdx.x;
  if (t >= BB * 1000) return;
  int b = t / 1000, k = t % 1000;
  const float* pw = pooled + b * CC;
  const float* cw = clsw + (size_t)k * CC;
  float acc = 0.f;
  for (int c = 0; c < CC; c++) {
    float sgn = (c == 0) ? -1.f : 1.f;
    acc = fmaf(pw[c] * sgn, cw[c], acc);
  }
  out[t] = 2.f + 2.f * (acc * (1.f / 3136.f)) + hb[k];
}

// ---------------- launch ----------------
extern "C" void kernel_launch(void* const* d_in, const int* in_sizes, int n_in,
                              void* d_out, int out_size, void* d_ws, size_t ws_size,
                              hipStream_t stream) {
  const float* x = (const float*)d_in[0];
  const float* c1w = (const float*)d_in[1];
  const float* c1b = (const float*)d_in[2];
  const float* bn1g = (const float*)d_in[3];
  const float* bn1b = (const float*)d_in[4];
  const float* c2w = (const float*)d_in[5];
  const float* c2b = (const float*)d_in[6];
  const float* bn2g = (const float*)d_in[7];
  const float* bn2b = (const float*)d_in[8];
  const float* c3w = (const float*)d_in[9];
  const float* c3b = (const float*)d_in[10];
  const float* bn3g = (const float*)d_in[11];
  const float* bn3b = (const float*)d_in[12];
  const float* pos = (const float*)d_in[13];
  const float* fc1w1 = (const float*)d_in[14];
  const float* fc1b1 = (const float*)d_in[15];
  const float* fc1s1 = (const float*)d_in[16];
  const float* fc1w2 = (const float*)d_in[17];
  const float* fc1b2 = (const float*)d_in[18];
  const float* fc1s2 = (const float*)d_in[19];
  const float* fc2w1 = (const float*)d_in[20];
  const float* fc2b1 = (const float*)d_in[21];
  const float* fc2s1 = (const float*)d_in[22];
  const float* fc2w2 = (const float*)d_in[23];
  const float* fc2b2 = (const float*)d_in[24];
  const float* fc2s2 = (const float*)d_in[25];
  const float* ffnw1 = (const float*)d_in[26];
  const float* ffnb1 = (const float*)d_in[27];
  const float* ffns1 = (const float*)d_in[28];
  const float* ffnw2 = (const float*)d_in[29];
  const float* ffnb2 = (const float*)d_in[30];
  const float* ffns2 = (const float*)d_in[31];
  const float* gcw = (const float*)d_in[32];
  const float* gcb = (const float*)d_in[33];
  const float* gcs = (const float*)d_in[34];
  const float* clsw = (const float*)d_in[35];
  const float* headb = (const float*)d_in[36];
  float* out = (float*)d_out;

  float* ws = (float*)d_ws;
  size_t off = 0;
  auto alloc = [&](size_t n) { float* p = ws + off; off += n; return p; };
  float* WT6 = alloc((size_t)6 * 6 * CC * CC);
  float* GCT = alloc((size_t)6 * 2 * CC * CC);
  float* W1T = alloc(27 * 160);
  float* C1 = alloc((size_t)BB * 112 * 112 * 160); // NHWC, post-relu
  float* C2 = alloc((size_t)RR * CC);              // NHWC tokens, post-relu
  float* C3 = alloc((size_t)RR * CC);              // NHWC tokens
  float* X  = alloc((size_t)RR * CC);
  // ---- layer temps; COL + conv weight transposes (stem-only) alias this span ----
  float* T1 = alloc((size_t)RR * CC);
  float* TMP = alloc((size_t)RR * CC);
  float* T2 = alloc((size_t)RR * CC);
  float* F  = alloc((size_t)RR * CC);
  float* Y  = alloc((size_t)RR * CC);
  float* T4 = alloc((size_t)RR * CC);
  float* T5 = alloc((size_t)RR * CC);
  float* T6 = alloc((size_t)RR * CC);
  float* CAT = alloc((size_t)RR * 2 * CC);
  // span [T1..CAT end) = 10*RR*CC = 20,070,400 floats
  float* COL = T1;                          // 6272*2880 = 18,063,360
  float* WT2 = COL + (size_t)RR * 2880;     // +460,800  -> 18,524,160
  float* WT3 = WT2 + (size_t)1440 * 320;    // +921,600  -> 19,445,760 < 20,070,400 OK
  float* DIST = alloc((size_t)BB * NN * NN);
  float* SQ = alloc(RR);
  float* NSBUF = alloc((size_t)RR * 2);
  float* POOL = alloc(BB * CC);
  int* IDX = (int*)(ws + off);
  off += (size_t)RR * 9;
  float2* NS = (float2*)NSBUF;

  {
    size_t tot = (size_t)6 * 6 * CC * CC;
    transpose6<<<dim3((unsigned)((tot + 255) / 256)), 256, 0, stream>>>(
        fc1w1, fc1w2, fc2w1, fc2w2, ffnw1, ffnw2, WT6);
    size_t tg = (size_t)6 * 2 * CC * CC;
    transpose_gc<<<dim3((unsigned)((tg + 255) / 256)), 256, 0, stream>>>(gcw, GCT);
    transpose_w1<<<dim3((160 * 27 + 255) / 256), 256, 0, stream>>>(c1w, W1T);
    transpose_conv<1440><<<dim3((1440 * 320 + 255) / 256), 256, 0, stream>>>(c2w, WT2);
    transpose_conv<2880><<<dim3((2880 * 320 + 255) / 256), 256, 0, stream>>>(c3w, WT3);
  }

  // ---- stem: conv1 direct (NHWC); conv2/conv3 = zero-pad im2col + GEMM ----
  conv1_kernel<<<dim3(BB * 112 * 112), 160, 0, stream>>>(x, W1T, c1b, bn1g, bn1b, C1);
  im2col_k<160, 112, 112, 2><<<dim3(RR), 256, 0, stream>>>(C1, COL);
  gemm_t<0, 2><<<dim3(SWZ), 128, 0, stream>>>(COL, WT2, c2b, bn2g, bn2b, nullptr, C2, 1440);
  im2col_k<320, 56, 56, 1><<<dim3(RR), 256, 0, stream>>>(C2, COL);
  gemm_t<0, 1><<<dim3(SWZ), 128, 0, stream>>>(COL, WT3, c3b, bn3g, bn3b, nullptr, C3, 2880);
  expmap_tok_kernel<<<dim3(RR), CC, 0, stream>>>(C3, pos, X);

  dim3 pgrid(49, 5, BB);
  for (int l = 0; l < 6; l++) {
    const float* w11 = WT6 + ((size_t)0 * 6 + l) * CC * CC;
    const float* w12 = WT6 + ((size_t)1 * 6 + l) * CC * CC;
    const float* w21 = WT6 + ((size_t)2 * 6 + l) * CC * CC;
    const float* w22 = WT6 + ((size_t)3 * 6 + l) * CC * CC;
    const float* wf1 = WT6 + ((size_t)4 * 6 + l) * CC * CC;
    const float* wf2 = WT6 + ((size_t)5 * 6 + l) * CC * CC;
    const float* wgc = GCT + (size_t)l * 2 * CC * CC;

    // ffn1 (fc1): g1 -> (norm scalars) -> g2(norm-on-load) -> n2(res=X)
    gemm_t<1, 0><<<dim3(SWZ), 128, 0, stream>>>(X, w11, fc1b1 + l * CC, nullptr, nullptr, nullptr, TMP, CC);
    norm_scal<<<RR / 4, 256, 0, stream>>>(TMP, fc1s1, l, NS);
    gemm_t<2, 0><<<dim3(SWZ), 128, 0, stream>>>(TMP, w12, fc1b2 + l * CC, nullptr, nullptr, NS, T1, CC);
    lorentz_norm<<<RR / 4, 256, 0, stream>>>(T1, fc1s2, l, X, T2);

    // f = P(T2)
    pperm_kernel<<<pgrid, 256, 0, stream>>>(T2, nullptr, F);

    // graph conv on F — batched dist + batched topk
    sq_kernel<<<RR / 4, 256, 0, stream>>>(F, SQ);
    dist_gemm_sym<<<dim3(1225, BB), 128, 0, stream>>>(F, SQ, DIST);
    if (l < 4)
      topk_kernel<9, 1><<<dim3(NN / 4, BB), 256, 0, stream>>>(DIST, IDX);
    else
      topk_kernel<18, 2><<<dim3(NN / 4, BB), 256, 0, stream>>>(DIST, IDX);
    gather_max_cat<<<RR, CC, 0, stream>>>(F, IDX, CAT);
    gemm_t<1, 0><<<dim3(SWZ), 128, 0, stream>>>(CAT, wgc, gcb + l * CC, nullptr, nullptr, nullptr, TMP, 2 * CC);
    lorentz_norm<<<RR / 4, 256, 0, stream>>>(TMP, gcs, l, nullptr, Y);

    // ffn2 (fc2): g4 -> (norm scalars) -> g5(norm-on-load) -> n5(res=Y)
    gemm_t<1, 0><<<dim3(SWZ), 128, 0, stream>>>(Y, w21, fc2b1 + l * CC, nullptr, nullptr, nullptr, TMP, CC);
    norm_scal<<<RR / 4, 256, 0, stream>>>(TMP, fc2s1, l, NS);
    gemm_t<2, 0><<<dim3(SWZ), 128, 0, stream>>>(TMP, w22, fc2b2 + l * CC, nullptr, nullptr, NS, T1, CC);
    lorentz_norm<<<RR / 4, 256, 0, stream>>>(T1, fc2s2, l, Y, T4);

    // T5 = P(T4) + X
    pperm_kernel<<<pgrid, 256, 0, stream>>>(T4, X, T5);

    // ffn3: g6 -> (norm scalars) -> g7(norm-on-load) -> n7(res=T5)
    gemm_t<1, 0><<<dim3(SWZ), 128, 0, stream>>>(T5, wf1, ffnb1 + l * CC, nullptr, nullptr, nullptr, TMP, CC);
    norm_scal<<<RR / 4, 256, 0, stream>>>(TMP, ffns1, l, NS);
    gemm_t<2, 0><<<dim3(SWZ), 128, 0, stream>>>(TMP, wf2, ffnb2 + l * CC, nullptr, nullptr, NS, T1, CC);
    lorentz_norm<<<RR / 4, 256, 0, stream>>>(T1, ffns2, l, T5, T6);

    // next block token view: X = P(T6)
    pperm_kernel<<<pgrid, 256, 0, stream>>>(T6, nullptr, X);
  }

  hipMemsetAsync(POOL, 0, (size_t)BB * CC * sizeof(float), stream);
  pool_kernel<<<dim3(49, BB), CC, 0, stream>>>(X, POOL);
  head_kernel<<<dim3((BB * 1000 + 255) / 256), 256, 0, stream>>>(POOL, clsw, headb, out);
}

// Round 16
// 3747.841 us; speedup vs baseline: 1.0223x; 1.0223x over previous
//
#include <hip/hip_runtime.h>
#include <cstdint>
#include <cstddef>

constexpr int CC = 320;     // channels
constexpr int NN = 3136;    // tokens (56*56)
constexpr int BB = 2;       // batch
constexpr int RR = BB * NN; // 6272 rows
constexpr float BN_INV_F = 0.9999950000374997f; // 1/sqrt(1+1e-5)

// ---------------- weight transposes: (l, co, ci) -> (l, ci, co) ----------------
__global__ __launch_bounds__(256) void transpose6(
    const float* __restrict__ w0, const float* __restrict__ w1,
    const float* __restrict__ w2, const float* __restrict__ w3,
    const float* __restrict__ w4, const float* __restrict__ w5,
    float* __restrict__ out) {
  size_t e = (size_t)blockIdx.x * 256 + threadIdx.x;
  const size_t per = (size_t)6 * CC * CC;
  if (e >= 6 * per) return;
  int m = (int)(e / per);
  size_t r = e % per;
  int l = (int)(r / (CC * CC));
  int q = (int)(r % (CC * CC));
  int ci = q / CC, co = q % CC;
  const float* src = (m == 0) ? w0 : (m == 1) ? w1 : (m == 2) ? w2
                   : (m == 3) ? w3 : (m == 4) ? w4 : w5;
  out[e] = src[(size_t)l * CC * CC + (size_t)co * CC + ci];
}

__global__ __launch_bounds__(256) void transpose_gc(const float* __restrict__ w,
                                                    float* __restrict__ out) {
  size_t e = (size_t)blockIdx.x * 256 + threadIdx.x;
  const size_t tot = (size_t)6 * 2 * CC * CC;
  if (e >= tot) return;
  int l = (int)(e / (2 * CC * CC));
  int q = (int)(e % (2 * CC * CC));
  int ci = q / CC, co = q % CC; // ci in [0,640)
  out[e] = w[(size_t)l * CC * 2 * CC + (size_t)co * 2 * CC + ci];
}

// w1 (160,3,3,3) OIHW -> (27,160)
__global__ __launch_bounds__(256) void transpose_w1(const float* __restrict__ w,
                                                    float* __restrict__ out) {
  int e = blockIdx.x * 256 + threadIdx.x;
  if (e >= 160 * 27) return;
  int oc = e / 27, k = e % 27;
  out[k * 160 + oc] = w[e];
}

// conv weight (320, K) -> (K, 320); k = ic*9+khw is the NATIVE inner order of OIHW
template <int K>
__global__ __launch_bounds__(256) void transpose_conv(const float* __restrict__ w,
                                                      float* __restrict__ out) {
  int e = blockIdx.x * 256 + threadIdx.x;
  if (e >= K * 320) return;
  int k = e / 320, co = e % 320;
  out[e] = w[(size_t)co * K + k];
}

// ---------------- conv1 direct: NCHW input -> NHWC output, bias+BN+relu ----------------
__global__ __launch_bounds__(160) void conv1_kernel(const float* __restrict__ x,
                                                    const float* __restrict__ w1t,
                                                    const float* __restrict__ cb,
                                                    const float* __restrict__ g,
                                                    const float* __restrict__ bt,
                                                    float* __restrict__ C1) {
  int pix = blockIdx.x;
  int oc = threadIdx.x;
  int b = pix / 12544;
  int r = pix % 12544;
  int oh = r / 112, ow = r % 112;
  int ih0 = 2 * oh - 1, iw0 = 2 * ow - 1;
  float acc = 0.f;
#pragma unroll
  for (int ic = 0; ic < 3; ic++) {
    const float* xc = x + ((size_t)(b * 3 + ic)) * 224 * 224;
#pragma unroll
    for (int kh = 0; kh < 3; kh++) {
      int ih = ih0 + kh;
      if (ih < 0 || ih >= 224) continue;
#pragma unroll
      for (int kw = 0; kw < 3; kw++) {
        int iw = iw0 + kw;
        if (iw < 0 || iw >= 224) continue;
        acc = fmaf(xc[(size_t)ih * 224 + iw], w1t[(ic * 9 + kh * 3 + kw) * 160 + oc], acc);
      }
    }
  }
  float y = (acc + cb[oc]) * (BN_INV_F * g[oc]) + bt[oc];
  C1[(size_t)pix * 160 + oc] = fmaxf(y, 0.f);
}

// ---------------- im2col with k = ic*9 + khw (zero-padded OOB; bit-exact via fmaf(0,w,a)=a) ----
template <int CIN, int IH, int IW, int S>
__global__ __launch_bounds__(256) void im2col_k(const float* __restrict__ src,
                                                float* __restrict__ COL) {
  constexpr int K = CIN * 9;
  int row = blockIdx.x;
  int b = row / 3136, pix = row % 3136;
  int oh = pix / 56, ow = pix % 56;
  int ih0 = S * oh - 1, iw0 = S * ow - 1;
  float* dst = COL + (size_t)row * K;
  for (int k = threadIdx.x; k < K; k += 256) {
    int ic = k / 9;
    int khw = k - ic * 9;
    int kh = khw / 3, kw = khw - kh * 3;
    int ih = ih0 + kh, iw = iw0 + kw;
    float v = 0.f;
    if (ih >= 0 && ih < IH && iw >= 0 && iw < IW)
      v = src[(((size_t)(b * IH + ih)) * IW + iw) * CIN + ic];
    dst[k] = v;
  }
}

// ---------------- expmap0 over channels (token-major NHWC input) + pos embed ----------------
__global__ __launch_bounds__(CC) void expmap_tok_kernel(const float* __restrict__ h,
                                                        const float* __restrict__ pos,
                                                        float* __restrict__ X) {
  int bn = blockIdx.x;
  int n = bn % NN;
  int c = threadIdx.x;
  float u = h[(size_t)bn * CC + c] + pos[(size_t)c * NN + n];
  float v = (c == 0) ? 0.f : u * u;
#pragma unroll
  for (int o = 32; o > 0; o >>= 1) v += __shfl_down(v, o, 64);
  __shared__ float red[5];
  __shared__ float fac[2];
  if ((c & 63) == 0) red[c >> 6] = v;
  __syncthreads();
  if (c == 0) {
    float s = red[0] + red[1] + red[2] + red[3] + red[4];
    float nrm = sqrtf(fmaxf(s, 1e-8f));
    fac[0] = coshf(nrm);
    fac[1] = sinhf(nrm) / nrm;
  }
  __syncthreads();
  X[(size_t)bn * CC + c] = (c == 0) ? fac[0] : fac[1] * u;
}

// ---------------- P permutation: V[n*C+c] = U[c*N+n]  (+ optional add[n*C+c]) ----------------
__global__ __launch_bounds__(256) void pperm_kernel(const float* __restrict__ U,
                                                    const float* __restrict__ add,
                                                    float* __restrict__ V) {
  __shared__ float t[64][65];
  int b = blockIdx.z;
  int n0 = blockIdx.x * 64;
  int c0 = blockIdx.y * 64;
  const float* Ub = U + (size_t)b * NN * CC;
  float* Vb = V + (size_t)b * NN * CC;
  const float* Ab = add ? add + (size_t)b * NN * CC : nullptr;
  int tx = threadIdx.x & 63;
  int ty = threadIdx.x >> 6; // 0..3
#pragma unroll
  for (int i = 0; i < 16; i++) {
    int c = ty * 16 + i;
    t[c][tx] = Ub[(size_t)(c0 + c) * NN + n0 + tx];
  }
  __syncthreads();
#pragma unroll
  for (int i = 0; i < 16; i++) {
    int n = ty * 16 + i;
    float v = t[tx][n];
    size_t o = (size_t)(n0 + n) * CC + c0 + tx;
    if (Ab) v += Ab[o];
    Vb[o] = v;
  }
}

// ---------------- GEMM: C[M,320] = op(A[M,K]) @ WT[K,320] + epilogue ----------------
// 64x64 tile, 128 threads, 8x4 microtile, BK=32, software-pipelined staging.
// Per-output k ascends monotonically with one accumulator => bit-identical.
// AMODE: 0 = raw A; 1 = relu(A); 2 = relu(LorentzNorm via per-row (tmv,rf) in NS)
// EPI: 0 = +bias; 1 = (acc+bias)*(BN_INV*g)+bt; 2 = EPI1 + relu
template <int AMODE, int EPI>
__global__ __launch_bounds__(128) void gemm_t(const float* __restrict__ A,
                                              const float* __restrict__ BW,
                                              const float* __restrict__ bias,
                                              const float* __restrict__ bng,
                                              const float* __restrict__ bnb,
                                              const float2* __restrict__ NS,
                                              float* __restrict__ C, int K) {
  __shared__ float As[32][68];
  __shared__ float Bs[32][68];
  int n0 = blockIdx.x * 64;
  int m0 = blockIdx.y * 64;
  int tid = threadIdx.x;
  int lm = tid >> 1;           // 0..63
  int lk8 = (tid & 1) * 8;     // 0 or 8
  int bk = tid >> 4;           // 0..7
  int bn = (tid & 15) << 2;    // 0..60
  int tm = (tid >> 4) << 3;    // 0..56 step 8
  int tn = (tid & 15) << 2;    // 0..60
  float acc[8][4] = {};
  float4 ra[4], rb[4];
  const float* aprow = A + (size_t)(m0 + lm) * K + lk8;
  float ns_t = 0.f, ns_r = 0.f;
  if (AMODE == 2) {
    float2 nv = NS[m0 + lm];
    ns_t = nv.x;
    ns_r = nv.y;
  }

  auto load_tile = [&](int k0) {
    const float* ap = aprow + k0;
    ra[0] = *(const float4*)ap;
    ra[1] = *(const float4*)(ap + 4);
    ra[2] = *(const float4*)(ap + 16);
    ra[3] = *(const float4*)(ap + 20);
#pragma unroll
    for (int h = 0; h < 4; h++)
      rb[h] = *(const float4*)(BW + (size_t)(k0 + bk + h * 8) * CC + n0 + bn);
  };
  auto store_tile = [&](int k0) {
#pragma unroll
    for (int h = 0; h < 2; h++) {
      float4 a0 = ra[h * 2], a1 = ra[h * 2 + 1];
      if (AMODE == 2) {
        int kbg = k0 + lk8 + h * 16;
        a0.x = (kbg == 0) ? ns_t : a0.x * ns_r;
        a0.y *= ns_r; a0.z *= ns_r; a0.w *= ns_r;
        a1.x *= ns_r; a1.y *= ns_r; a1.z *= ns_r; a1.w *= ns_r;
      }
      if (AMODE >= 1) {
        a0.x = fmaxf(a0.x, 0.f); a0.y = fmaxf(a0.y, 0.f);
        a0.z = fmaxf(a0.z, 0.f); a0.w = fmaxf(a0.w, 0.f);
        a1.x = fmaxf(a1.x, 0.f); a1.y = fmaxf(a1.y, 0.f);
        a1.z = fmaxf(a1.z, 0.f); a1.w = fmaxf(a1.w, 0.f);
      }
      int kb = lk8 + h * 16;
      As[kb + 0][lm] = a0.x; As[kb + 1][lm] = a0.y;
      As[kb + 2][lm] = a0.z; As[kb + 3][lm] = a0.w;
      As[kb + 4][lm] = a1.x; As[kb + 5][lm] = a1.y;
      As[kb + 6][lm] = a1.z; As[kb + 7][lm] = a1.w;
    }
#pragma unroll
    for (int h = 0; h < 4; h++)
      *(float4*)&Bs[bk + h * 8][bn] = rb[h];
  };
  auto compute = [&]() {
#pragma unroll
    for (int k = 0; k < 32; k++) {
      float4 av0 = *(const float4*)&As[k][tm];
      float4 av1 = *(const float4*)&As[k][tm + 4];
      float4 bv = *(const float4*)&Bs[k][tn];
      float aa[8] = {av0.x, av0.y, av0.z, av0.w, av1.x, av1.y, av1.z, av1.w};
      float bb[4] = {bv.x, bv.y, bv.z, bv.w};
#pragma unroll
      for (int i = 0; i < 8; i++)
#pragma unroll
        for (int j = 0; j < 4; j++) acc[i][j] = fmaf(aa[i], bb[j], acc[i][j]);
    }
  };

  load_tile(0);
  store_tile(0);
  __syncthreads();
  for (int k0 = 32; k0 < K; k0 += 32) {
    load_tile(k0);   // in flight during compute
    compute();
    __syncthreads();
    store_tile(k0);
    __syncthreads();
  }
  compute();

  float4 bv = *(const float4*)(bias + n0 + tn);
  float bb[4] = {bv.x, bv.y, bv.z, bv.w};
  float gg[4], tt[4];
  if (EPI >= 1) {
    float4 gv = *(const float4*)(bng + n0 + tn);
    float4 tv = *(const float4*)(bnb + n0 + tn);
    gg[0] = gv.x; gg[1] = gv.y; gg[2] = gv.z; gg[3] = gv.w;
    tt[0] = tv.x; tt[1] = tv.y; tt[2] = tv.z; tt[3] = tv.w;
  }
#pragma unroll
  for (int i = 0; i < 8; i++) {
    float o[4];
#pragma unroll
    for (int j = 0; j < 4; j++) {
      float y = acc[i][j] + bb[j];
      if (EPI >= 1) y = y * (BN_INV_F * gg[j]) + tt[j];
      if (EPI == 2) y = fmaxf(y, 0.f);
      o[j] = y;
    }
    float4 ov = {o[0], o[1], o[2], o[3]};
    *(float4*)(C + (size_t)(m0 + tm + i) * CC + n0 + tn) = ov;
  }
}

// ---------------- Lorentz row normalization (+ optional residual) ----------------
__global__ __launch_bounds__(256) void lorentz_norm(const float* __restrict__ Y,
                                                    const float* __restrict__ logs, int l,
                                                    const float* __restrict__ res1,
                                                    float* __restrict__ out) {
  int lane = threadIdx.x & 63;
  size_t row = (size_t)blockIdx.x * 4 + (threadIdx.x >> 6);
  const float* y = Y + row * CC;
  float v[5];
  float ss = 0.f;
#pragma unroll
  for (int q = 0; q < 5; q++) {
    v[q] = y[q * 64 + lane];
    float z = v[q] * v[q];
    if (q == 0 && lane == 0) z = 0.f;
    ss += z;
  }
#pragma unroll
  for (int o = 32; o > 0; o >>= 1) ss += __shfl_down(ss, o, 64);
  ss = __shfl(ss, 0, 64);
  float y0 = __shfl(v[0], 0, 64);
  float scale = expf(logs[l]);
  float tmv = scale / (1.f + expf(-y0)) + 1.1f;
  float rf = sqrtf((tmv * tmv - 1.f) / fmaxf(ss, 1e-8f));
#pragma unroll
  for (int q = 0; q < 5; q++) {
    int c = q * 64 + lane;
    float o = (c == 0) ? tmv : v[q] * rf;
    if (res1) o += res1[row * CC + c];
    out[row * CC + c] = o;
  }
}

// ---------------- norm scalars only: NS[row] = (tmv, rf)  (exact lorentz_norm scalar path) ----
__global__ __launch_bounds__(256) void norm_scal(const float* __restrict__ Y,
                                                 const float* __restrict__ logs, int l,
                                                 float2* __restrict__ NS) {
  int lane = threadIdx.x & 63;
  size_t row = (size_t)blockIdx.x * 4 + (threadIdx.x >> 6);
  const float* y = Y + row * CC;
  float v[5];
  float ss = 0.f;
#pragma unroll
  for (int q = 0; q < 5; q++) {
    v[q] = y[q * 64 + lane];
    float z = v[q] * v[q];
    if (q == 0 && lane == 0) z = 0.f;
    ss += z;
  }
#pragma unroll
  for (int o = 32; o > 0; o >>= 1) ss += __shfl_down(ss, o, 64);
  ss = __shfl(ss, 0, 64);
  float y0 = __shfl(v[0], 0, 64);
  float scale = expf(logs[l]);
  float tmv = scale / (1.f + expf(-y0)) + 1.1f;
  float rf = sqrtf((tmv * tmv - 1.f) / fmaxf(ss, 1e-8f));
  if (lane == 0) NS[row] = make_float2(tmv, rf);
}

// ---------------- per-row squared norms ----------------
__global__ __launch_bounds__(256) void sq_kernel(const float* __restrict__ Y,
                                                 float* __restrict__ sq) {
  int lane = threadIdx.x & 63;
  size_t row = (size_t)blockIdx.x * 4 + (threadIdx.x >> 6);
  const float* y = Y + row * CC;
  float ss = 0.f;
#pragma unroll
  for (int q = 0; q < 5; q++) {
    float v = y[q * 64 + lane];
    ss += v * v;
  }
#pragma unroll
  for (int o = 32; o > 0; o >>= 1) ss += __shfl_down(ss, o, 64);
  if (lane == 0) sq[row] = ss;
}

// ---------------- symmetric distance, batched over B: upper-triangle tiles ----------------
__global__ __launch_bounds__(128) void dist_gemm_sym(const float* __restrict__ Yall,
                                                     const float* __restrict__ sqall,
                                                     float* __restrict__ Dall) {
  __shared__ float S[2][32][68];
  auto As = S[0];
  auto Bs = S[1];
  int tid = threadIdx.x;
  int batch = blockIdx.y;
  const float* Y = Yall + (size_t)batch * NN * CC;
  const float* sq = sqall + (size_t)batch * NN;
  float* D = Dall + (size_t)batch * NN * NN;
  int t = blockIdx.x;
  int bi = 0, rem = t;
  while (rem >= 49 - bi) { rem -= 49 - bi; bi++; }
  int bj = bi + rem;
  int i0 = bi * 64, j0 = bj * 64;
  int lm = tid >> 1;
  int lk8 = (tid & 1) * 8;
  int tm = (tid >> 4) << 3;
  int tn = (tid & 15) << 2;
  float acc[8][4] = {};
  float4 ra[4], rb[4];
  const float* aprow = Y + (size_t)(i0 + lm) * CC + lk8;
  const float* bprow = Y + (size_t)(j0 + lm) * CC + lk8;

  auto load_tile = [&](int k0) {
    const float* ap = aprow + k0;
    ra[0] = *(const float4*)ap;
    ra[1] = *(const float4*)(ap + 4);
    ra[2] = *(const float4*)(ap + 16);
    ra[3] = *(const float4*)(ap + 20);
    const float* bp = bprow + k0;
    rb[0] = *(const float4*)bp;
    rb[1] = *(const float4*)(bp + 4);
    rb[2] = *(const float4*)(bp + 16);
    rb[3] = *(const float4*)(bp + 20);
  };
  auto store_tile = [&]() {
#pragma unroll
    for (int h = 0; h < 2; h++) {
      int kb = lk8 + h * 16;
      float4 a0 = ra[h * 2], a1 = ra[h * 2 + 1];
      As[kb + 0][lm] = a0.x; As[kb + 1][lm] = a0.y;
      As[kb + 2][lm] = a0.z; As[kb + 3][lm] = a0.w;
      As[kb + 4][lm] = a1.x; As[kb + 5][lm] = a1.y;
      As[kb + 6][lm] = a1.z; As[kb + 7][lm] = a1.w;
      float4 b0 = rb[h * 2], b1 = rb[h * 2 + 1];
      Bs[kb + 0][lm] = b0.x; Bs[kb + 1][lm] = b0.y;
      Bs[kb + 2][lm] = b0.z; Bs[kb + 3][lm] = b0.w;
      Bs[kb + 4][lm] = b1.x; Bs[kb + 5][lm] = b1.y;
      Bs[kb + 6][lm] = b1.z; Bs[kb + 7][lm] = b1.w;
    }
  };
  auto compute = [&]() {
#pragma unroll
    for (int k = 0; k < 32; k++) {
      float4 av0 = *(const float4*)&As[k][tm];
      float4 av1 = *(const float4*)&As[k][tm + 4];
      float4 bv = *(const float4*)&Bs[k][tn];
      float aa[8] = {av0.x, av0.y, av0.z, av0.w, av1.x, av1.y, av1.z, av1.w};
      float bb[4] = {bv.x, bv.y, bv.z, bv.w};
#pragma unroll
      for (int i = 0; i < 8; i++)
#pragma unroll
        for (int j = 0; j < 4; j++) acc[i][j] = fmaf(aa[i], bb[j], acc[i][j]);
    }
  };

  load_tile(0);
  store_tile();
  __syncthreads();
  for (int k0 = 32; k0 < CC; k0 += 32) {
    load_tile(k0);
    compute();
    __syncthreads();
    store_tile();
    __syncthreads();
  }
  compute();

  float sqi[8], sqj[4];
#pragma unroll
  for (int i = 0; i < 8; i++) sqi[i] = sq[i0 + tm + i];
#pragma unroll
  for (int j = 0; j < 4; j++) sqj[j] = sq[j0 + tn + j];
  float o[8][4];
#pragma unroll
  for (int i = 0; i < 8; i++) {
#pragma unroll
    for (int j = 0; j < 4; j++)
      o[i][j] = sqi[i] + sqj[j] - 2.f * acc[i][j];
    float4 ov = {o[i][0], o[i][1], o[i][2], o[i][3]};
    *(float4*)(D + (size_t)(i0 + tm + i) * NN + j0 + tn) = ov;
  }
  if (bi != bj) {
    __syncthreads();
    float* flat = &S[0][0][0];
#pragma unroll
    for (int i = 0; i < 8; i++)
#pragma unroll
      for (int j = 0; j < 4; j++)
        flat[(tn + j) * 65 + tm + i] = o[i][j];
    __syncthreads();
#pragma unroll
    for (int r = 0; r < 4; r++) {
      int row = tn + r;
      float4 w0, w1;
      w0.x = flat[row * 65 + tm + 0]; w0.y = flat[row * 65 + tm + 1];
      w0.z = flat[row * 65 + tm + 2]; w0.w = flat[row * 65 + tm + 3];
      w1.x = flat[row * 65 + tm + 4]; w1.y = flat[row * 65 + tm + 5];
      w1.z = flat[row * 65 + tm + 6]; w1.w = flat[row * 65 + tm + 7];
      *(float4*)(D + (size_t)(j0 + row) * NN + i0 + tm) = w0;
      *(float4*)(D + (size_t)(j0 + row) * NN + i0 + tm + 4) = w1;
    }
  }
}

// ---------------- exact top-k, batched over B (jax tie-break), wave per row ----------------
template <int KT, int DIL>
__global__ __launch_bounds__(256) void topk_kernel(const float* __restrict__ Dall,
                                                   int* __restrict__ idxall) {
  int lane = threadIdx.x & 63;
  int batch = blockIdx.y;
  int row = blockIdx.x * 4 + (threadIdx.x >> 6); // row within one batch
  const float* d = Dall + (size_t)batch * NN * NN + (size_t)row * NN;
  int* idxout = idxall + (size_t)batch * NN * 9;
  float ld[KT];
  int li[KT];
#pragma unroll
  for (int q = 0; q < KT; q++) { ld[q] = 3.4e38f; li[q] = 0x7FFFFFFF; }
  for (int t = 0; t < NN / 64; t++) {
    int j = t * 64 + lane;
    float x = d[j];
    if (x < ld[KT - 1]) {
      ld[KT - 1] = x;
      li[KT - 1] = j;
#pragma unroll
      for (int p = KT - 1; p > 0; p--) {
        if (ld[p] < ld[p - 1]) {
          float tf = ld[p]; ld[p] = ld[p - 1]; ld[p - 1] = tf;
          int ti = li[p]; li[p] = li[p - 1]; li[p - 1] = ti;
        }
      }
    }
  }
#pragma unroll 1
  for (int q = 0; q < KT; q++) {
    float bd = ld[0];
    int bi = li[0];
#pragma unroll
    for (int s = 32; s > 0; s >>= 1) {
      float od = __shfl_xor(bd, s, 64);
      int oi = __shfl_xor(bi, s, 64);
      if (od < bd || (od == bd && oi < bi)) { bd = od; bi = oi; }
    }
    if (ld[0] == bd && li[0] == bi) {
#pragma unroll
      for (int p = 0; p < KT - 1; p++) { ld[p] = ld[p + 1]; li[p] = li[p + 1]; }
      ld[KT - 1] = 3.4e38f;
      li[KT - 1] = 0x7FFFFFFF;
    }
    if (lane == 0 && (q % DIL) == 0) idxout[(size_t)row * 9 + q / DIL] = bi;
  }
}

// ---------------- neighbor max + concat [f, max_j f_j - f_i] ----------------
__global__ __launch_bounds__(CC) void gather_max_cat(const float* __restrict__ Y,
                                                     const int* __restrict__ idx,
                                                     float* __restrict__ cat) {
  int bn = blockIdx.x;
  int c = threadIdx.x;
  int b = bn / NN;
  float yc = Y[(size_t)bn * CC + c];
  const int* ip = idx + (size_t)bn * 9;
  float mx = -3.4e38f;
#pragma unroll
  for (int q = 0; q < 9; q++) {
    int j = ip[q];
    mx = fmaxf(mx, Y[((size_t)b * NN + j) * CC + c]);
  }
  cat[(size_t)bn * 2 * CC + c] = yc;
  cat[(size_t)bn * 2 * CC + CC + c] = mx - yc;
}

// ---------------- pooling + head ----------------
__global__ __launch_bounds__(CC) void pool_kernel(const float* __restrict__ X,
                                                  float* __restrict__ pooled) {
  int b = blockIdx.y;
  int chunk = blockIdx.x;
  int c = threadIdx.x;
  const float* p = X + ((size_t)b * NN + (size_t)chunk * 64) * CC + c;
  float s = 0.f;
#pragma unroll
  for (int q = 0; q < 64; q++) s += p[(size_t)q * CC];
  atomicAdd(&pooled[b * CC + c], s);
}

__global__ __launch_bounds__(256) void head_kernel(const float* __restrict__ pooled,
                                                   const float* __restrict__ clsw,
                                                   const float* __restrict__ hb,
                                                   float* __restrict__ out) {
  int t = blockIdx.x * 256 + threadIdx.x;
  if (t >= BB * 1000) return;
  int b = t / 1000, k = t % 1000;
  const float* pw = pooled + b * CC;
  const float* cw = clsw + (size_t)k * CC;
  float acc = 0.f;
  for (int c = 0; c < CC; c++) {
    float sgn = (c == 0) ? -1.f : 1.f;
    acc = fmaf(pw[c] * sgn, cw[c], acc);
  }
  out[t] = 2.f + 2.f * (acc * (1.f / 3136.f)) + hb[k];
}

// ---------------- launch ----------------
extern "C" void kernel_launch(void* const* d_in, const int* in_sizes, int n_in,
                              void* d_out, int out_size, void* d_ws, size_t ws_size,
                              hipStream_t stream) {
  const float* x = (const float*)d_in[0];
  const float* c1w = (const float*)d_in[1];
  const float* c1b = (const float*)d_in[2];
  const float* bn1g = (const float*)d_in[3];
  const float* bn1b = (const float*)d_in[4];
  const float* c2w = (const float*)d_in[5];
  const float* c2b = (const float*)d_in[6];
  const float* bn2g = (const float*)d_in[7];
  const float* bn2b = (const float*)d_in[8];
  const float* c3w = (const float*)d_in[9];
  const float* c3b = (const float*)d_in[10];
  const float* bn3g = (const float*)d_in[11];
  const float* bn3b = (const float*)d_in[12];
  const float* pos = (const float*)d_in[13];
  const float* fc1w1 = (const float*)d_in[14];
  const float* fc1b1 = (const float*)d_in[15];
  const float* fc1s1 = (const float*)d_in[16];
  const float* fc1w2 = (const float*)d_in[17];
  const float* fc1b2 = (const float*)d_in[18];
  const float* fc1s2 = (const float*)d_in[19];
  const float* fc2w1 = (const float*)d_in[20];
  const float* fc2b1 = (const float*)d_in[21];
  const float* fc2s1 = (const float*)d_in[22];
  const float* fc2w2 = (const float*)d_in[23];
  const float* fc2b2 = (const float*)d_in[24];
  const float* fc2s2 = (const float*)d_in[25];
  const float* ffnw1 = (const float*)d_in[26];
  const float* ffnb1 = (const float*)d_in[27];
  const float* ffns1 = (const float*)d_in[28];
  const float* ffnw2 = (const float*)d_in[29];
  const float* ffnb2 = (const float*)d_in[30];
  const float* ffns2 = (const float*)d_in[31];
  const float* gcw = (const float*)d_in[32];
  const float* gcb = (const float*)d_in[33];
  const float* gcs = (const float*)d_in[34];
  const float* clsw = (const float*)d_in[35];
  const float* headb = (const float*)d_in[36];
  float* out = (float*)d_out;

  float* ws = (float*)d_ws;
  size_t off = 0;
  auto alloc = [&](size_t n) { float* p = ws + off; off += n; return p; };
  float* WT6 = alloc((size_t)6 * 6 * CC * CC);
  float* GCT = alloc((size_t)6 * 2 * CC * CC);
  float* W1T = alloc(27 * 160);
  float* C1 = alloc((size_t)BB * 112 * 112 * 160); // NHWC, post-relu
  float* C2 = alloc((size_t)RR * CC);              // NHWC tokens, post-relu
  float* C3 = alloc((size_t)RR * CC);              // NHWC tokens
  float* X  = alloc((size_t)RR * CC);
  // ---- layer temps; COL + conv weight transposes (stem-only) alias this span ----
  float* T1 = alloc((size_t)RR * CC);
  float* TMP = alloc((size_t)RR * CC);
  float* T2 = alloc((size_t)RR * CC);
  float* F  = alloc((size_t)RR * CC);
  float* Y  = alloc((size_t)RR * CC);
  float* T4 = alloc((size_t)RR * CC);
  float* T5 = alloc((size_t)RR * CC);
  float* T6 = alloc((size_t)RR * CC);
  float* CAT = alloc((size_t)RR * 2 * CC);
  // span [T1..CAT end) = 10*RR*CC = 20,070,400 floats
  float* COL = T1;                          // 6272*2880 = 18,063,360
  float* WT2 = COL + (size_t)RR * 2880;     // +460,800  -> 18,524,160
  float* WT3 = WT2 + (size_t)1440 * 320;    // +921,600  -> 19,445,760 < 20,070,400 OK
  float* DIST = alloc((size_t)BB * NN * NN);
  float* SQ = alloc(RR);
  float* NSBUF = alloc((size_t)RR * 2);
  float* POOL = alloc(BB * CC);
  int* IDX = (int*)(ws + off);
  off += (size_t)RR * 9;
  float2* NS = (float2*)NSBUF;

  {
    size_t tot = (size_t)6 * 6 * CC * CC;
    transpose6<<<dim3((unsigned)((tot + 255) / 256)), 256, 0, stream>>>(
        fc1w1, fc1w2, fc2w1, fc2w2, ffnw1, ffnw2, WT6);
    size_t tg = (size_t)6 * 2 * CC * CC;
    transpose_gc<<<dim3((unsigned)((tg + 255) / 256)), 256, 0, stream>>>(gcw, GCT);
    transpose_w1<<<dim3((160 * 27 + 255) / 256), 256, 0, stream>>>(c1w, W1T);
    transpose_conv<1440><<<dim3((1440 * 320 + 255) / 256), 256, 0, stream>>>(c2w, WT2);
    transpose_conv<2880><<<dim3((2880 * 320 + 255) / 256), 256, 0, stream>>>(c3w, WT3);
  }

  dim3 ggrid(5, 98);  // linear 2D grid (no XCD swizzle — R15 showed it regresses)

  // ---- stem: conv1 direct (NHWC); conv2/conv3 = zero-pad im2col + GEMM ----
  conv1_kernel<<<dim3(BB * 112 * 112), 160, 0, stream>>>(x, W1T, c1b, bn1g, bn1b, C1);
  im2col_k<160, 112, 112, 2><<<dim3(RR), 256, 0, stream>>>(C1, COL);
  gemm_t<0, 2><<<ggrid, 128, 0, stream>>>(COL, WT2, c2b, bn2g, bn2b, nullptr, C2, 1440);
  im2col_k<320, 56, 56, 1><<<dim3(RR), 256, 0, stream>>>(C2, COL);
  gemm_t<0, 1><<<ggrid, 128, 0, stream>>>(COL, WT3, c3b, bn3g, bn3b, nullptr, C3, 2880);
  expmap_tok_kernel<<<dim3(RR), CC, 0, stream>>>(C3, pos, X);

  dim3 pgrid(49, 5, BB);
  for (int l = 0; l < 6; l++) {
    const float* w11 = WT6 + ((size_t)0 * 6 + l) * CC * CC;
    const float* w12 = WT6 + ((size_t)1 * 6 + l) * CC * CC;
    const float* w21 = WT6 + ((size_t)2 * 6 + l) * CC * CC;
    const float* w22 = WT6 + ((size_t)3 * 6 + l) * CC * CC;
    const float* wf1 = WT6 + ((size_t)4 * 6 + l) * CC * CC;
    const float* wf2 = WT6 + ((size_t)5 * 6 + l) * CC * CC;
    const float* wgc = GCT + (size_t)l * 2 * CC * CC;

    // ffn1 (fc1): g1 -> (norm scalars) -> g2(norm-on-load) -> n2(res=X)
    gemm_t<1, 0><<<ggrid, 128, 0, stream>>>(X, w11, fc1b1 + l * CC, nullptr, nullptr, nullptr, TMP, CC);
    norm_scal<<<RR / 4, 256, 0, stream>>>(TMP, fc1s1, l, NS);
    gemm_t<2, 0><<<ggrid, 128, 0, stream>>>(TMP, w12, fc1b2 + l * CC, nullptr, nullptr, NS, T1, CC);
    lorentz_norm<<<RR / 4, 256, 0, stream>>>(T1, fc1s2, l, X, T2);

    // f = P(T2)
    pperm_kernel<<<pgrid, 256, 0, stream>>>(T2, nullptr, F);

    // graph conv on F — batched dist + batched topk
    sq_kernel<<<RR / 4, 256, 0, stream>>>(F, SQ);
    dist_gemm_sym<<<dim3(1225, BB), 128, 0, stream>>>(F, SQ, DIST);
    if (l < 4)
      topk_kernel<9, 1><<<dim3(NN / 4, BB), 256, 0, stream>>>(DIST, IDX);
    else
      topk_kernel<18, 2><<<dim3(NN / 4, BB), 256, 0, stream>>>(DIST, IDX);
    gather_max_cat<<<RR, CC, 0, stream>>>(F, IDX, CAT);
    gemm_t<1, 0><<<ggrid, 128, 0, stream>>>(CAT, wgc, gcb + l * CC, nullptr, nullptr, nullptr, TMP, 2 * CC);
    lorentz_norm<<<RR / 4, 256, 0, stream>>>(TMP, gcs, l, nullptr, Y);

    // ffn2 (fc2): g4 -> (norm scalars) -> g5(norm-on-load) -> n5(res=Y)
    gemm_t<1, 0><<<ggrid, 128, 0, stream>>>(Y, w21, fc2b1 + l * CC, nullptr, nullptr, nullptr, TMP, CC);
    norm_scal<<<RR / 4, 256, 0, stream>>>(TMP, fc2s1, l, NS);
    gemm_t<2, 0><<<ggrid, 128, 0, stream>>>(TMP, w22, fc2b2 + l * CC, nullptr, nullptr, NS, T1, CC);
    lorentz_norm<<<RR / 4, 256, 0, stream>>>(T1, fc2s2, l, Y, T4);

    // T5 = P(T4) + X
    pperm_kernel<<<pgrid, 256, 0, stream>>>(T4, X, T5);

    // ffn3: g6 -> (norm scalars) -> g7(norm-on-load) -> n7(res=T5)
    gemm_t<1, 0><<<ggrid, 128, 0, stream>>>(T5, wf1, ffnb1 + l * CC, nullptr, nullptr, nullptr, TMP, CC);
    norm_scal<<<RR / 4, 256, 0, stream>>>(TMP, ffns1, l, NS);
    gemm_t<2, 0><<<ggrid, 128, 0, stream>>>(TMP, wf2, ffnb2 + l * CC, nullptr, nullptr, NS, T1, CC);
    lorentz_norm<<<RR / 4, 256, 0, stream>>>(T1, ffns2, l, T5, T6);

    // next block token view: X = P(T6)
    pperm_kernel<<<pgrid, 256, 0, stream>>>(T6, nullptr, X);
  }

  hipMemsetAsync(POOL, 0, (size_t)BB * CC * sizeof(float), stream);
  pool_kernel<<<dim3(49, BB), CC, 0, stream>>>(X, POOL);
  head_kernel<<<dim3((BB * 1000 + 255) / 256), 256, 0, stream>>>(POOL, clsw, headb, out);
}